// Round 3
// baseline (2066.726 us; speedup 1.0000x reference)
//
#include <hip/hip_runtime.h>
#include <hip/hip_bf16.h>

// ---------------------------------------------------------------------------
// Fused residual-MLP (N=65536, HID=512, NB=20) for gfx950.  Round 11.
//
// R10 post-mortem: absmax 0.4194 = max|ref| -> output zeroed; 157.7KB dynamic
// LDS is past the verified <=128KB/WG envelope (or the new 2-barrier template
// raced). Lesson: only proven sync structures. R9 (64x64/wave) PASSED but
// spilled (~200 regs vs 128 cap).
// Resource model (R8, per GEMM phase per CU, measured rates): MFMA 2.5k cyc,
// A-LDS 1.25MB@85B/cyc = 14.7k, B-L2 512KB@56B/cyc = 9.1k, epi 2.5k;
// sum 28.8k == measured 28k. A-LDS (16 waves x full 64-row panel) dominates.
// R11 = R8's exact 4-barrier/single-hn/stats-in-gemm control flow, re-tiled:
//   16 waves = 2 row-halves x 8 col-groups; wave = 32 rows x 64 cols
//   (4 interleaved 16-col tiles, R9's proven B-pack layout).
//   A-LDS per GEMM 1MB -> 512KB. Regs: acc32(AGPR)+h32+a8+b16+misc ~ 110
//   <= 128 cap (R8's own budget) -> no spill. LDS 67,072 B (R8-proven size).
// ---------------------------------------------------------------------------

typedef float  fvec4 __attribute__((ext_vector_type(4)));
typedef __bf16 bvec8 __attribute__((ext_vector_type(8)));

#define HN_STRIDE 520                 // ushorts per hn row (proven R1-R8)
#define WCHUNK    32768               // ushorts per (b,slot,cg) chunk, cg=0..7
#define SMEM_BYTES (64*HN_STRIDE*2 + 64*8)       // 66560 + 512 = 67072
#define WPK_USHORTS ((size_t)20*2*8*WCHUNK)      // 10,485,760

__device__ __forceinline__ unsigned int f2bf(float v) {
    unsigned int u = __float_as_uint(v);
    return (u + 0x7fffu + ((u >> 16) & 1u)) >> 16;   // RNE to bf16
}
__device__ __forceinline__ unsigned int pkbf(float a, float b) {
    __hip_bfloat162 t = __float22bfloat162_rn(make_float2(a, b));
    unsigned int r;
    __builtin_memcpy(&r, &t, 4);                     // v_cvt_pk_bf16_f32
    return r;
}
__device__ __forceinline__ float silu_f(float v) {
    return v * (1.0f / (1.0f + __expf(-v)));
}

// ---- weight pre-pack: bf16(gamma_k * W[b][k][n]) in MFMA B-fragment order -
// chunk = cg + 8*slot + 16*b ; within chunk: [kc][t][lane] x 16B   (R9-proven)
// col mapping: n = cg*64 + (lane&15)*4 + t
__global__ __launch_bounds__(256) void pack_weights(
        const float* __restrict__ w1, const float* __restrict__ w2,
        const float* __restrict__ g1, const float* __restrict__ g2,
        unsigned short* __restrict__ pk) {
    int tid = blockIdx.x * 256 + threadIdx.x;
    int l  = tid & 63;
    int f  = tid >> 6;
    int t  = f & 3;
    int kc = (f >> 2) & 15;
    int w  = (f >> 6) & 7;
    int g  = (f >> 9) & 1;
    int b  = f >> 10;
    const float* src = g ? w2 : w1;
    const float* gs  = (g ? g2 : g1) + b * 512;
    int k0 = kc * 32 + (l >> 4) * 8;
    int n  = w * 64 + (l & 15) * 4 + t;
    const float* s = src + ((size_t)b * 512 + k0) * 512 + n;
    unsigned int r[4];
#pragma unroll
    for (int j = 0; j < 4; ++j) {
        float ga = gs[k0 + 2 * j];
        float gb = gs[k0 + 2 * j + 1];
        unsigned int lo = f2bf(ga * s[(size_t)(2*j) * 512]);
        unsigned int hi = f2bf(gb * s[(size_t)(2*j + 1) * 512]);
        r[j] = lo | (hi << 16);
    }
    *(uint4*)(pk + (size_t)tid * 8) = make_uint4(r[0], r[1], r[2], r[3]);
}

// ---- u/vc precompute: u_n = sum_j g_j W_jn ; vc_n = sum_j beta_j W_jn + fcb_n
__global__ __launch_bounds__(512) void make_uv(
        const float* __restrict__ w1, const float* __restrict__ w2,
        const float* __restrict__ g1, const float* __restrict__ bl1,
        const float* __restrict__ cb1,
        const float* __restrict__ g2, const float* __restrict__ bl2,
        const float* __restrict__ cb2,
        float* __restrict__ uv) {
    int b = blockIdx.x >> 1, slot = blockIdx.x & 1, n = threadIdx.x;
    const float* W  = (slot ? w2 : w1) + (size_t)b * 512 * 512;
    const float* g  = (slot ? g2 : g1) + b * 512;
    const float* bl = (slot ? bl2 : bl1) + b * 512;
    const float* cb = (slot ? cb2 : cb1) + b * 512;
    float u = 0.f, v = 0.f;
    for (int j = 0; j < 512; ++j) {
        float wv = W[(size_t)j * 512 + n];
        u = fmaf(g[j], wv, u);
        v = fmaf(bl[j], wv, v);
    }
    uv[((b * 2 + slot) * 2 + 0) * 512 + n] = u;
    uv[((b * 2 + slot) * 2 + 1) * 512 + n] = v + cb[n];
}

__device__ __forceinline__ void acc_u32(unsigned int u, float& s, float& ss) {
    float lo = __uint_as_float(u << 16);
    float hi = __uint_as_float(u & 0xFFFF0000u);
    s += lo + hi;
    ss = __builtin_fmaf(lo, lo, ss);
    ss = __builtin_fmaf(hi, hi, ss);
}

// ---- GEMM (wave = 32 rows x 64 cols) with LN-stats interleaved (R8 stats) -
// Stats of the CURRENT hn contents land in mv (visible after next barrier).
__device__ __forceinline__ void gemm_red(
        fvec4 acc[2][4], const unsigned short* hn,
        const unsigned short* __restrict__ wp, const uint4* pre,
        float2* mv, int l, int c, int q, int tid, int rbase) {
    const uint4* wp4 = (const uint4*)wp;
    const int r = tid >> 4, j = tid & 15;
    float s = 0.f, ss = 0.f;
#pragma unroll
    for (int kc = 0; kc < 16; ++kc) {
        bvec8 a[2];
        uint4 br[4];
#pragma unroll
        for (int rb = 0; rb < 2; ++rb)
            a[rb] = *(const bvec8*)(hn + (rbase + rb * 16 + c) * HN_STRIDE + kc * 32 + q * 8);
        if (kc == 0) {
#pragma unroll
            for (int t = 0; t < 4; ++t) br[t] = pre[t];
        } else {
#pragma unroll
            for (int t = 0; t < 4; ++t) br[t] = wp4[(kc * 4 + t) * 64 + l];
        }
        if (kc >= 4 && kc < 8) {   // 4 stats chunks hidden under the MFMA stream
            uint4 pv = *(const uint4*)(hn + r * HN_STRIDE + (j + 16 * (kc - 4)) * 8);
            acc_u32(pv.x, s, ss); acc_u32(pv.y, s, ss);
            acc_u32(pv.z, s, ss); acc_u32(pv.w, s, ss);
        }
#pragma unroll
        for (int rb = 0; rb < 2; ++rb) {
#pragma unroll
            for (int t = 0; t < 4; ++t) {
                bvec8 bb;
                __builtin_memcpy(&bb, &br[t], 16);
                acc[rb][t] = __builtin_amdgcn_mfma_f32_16x16x32_bf16(a[rb], bb, acc[rb][t], 0, 0, 0);
            }
        }
    }
    s += __shfl_xor(s, 1); ss += __shfl_xor(ss, 1);
    s += __shfl_xor(s, 2); ss += __shfl_xor(ss, 2);
    s += __shfl_xor(s, 4); ss += __shfl_xor(ss, 4);
    s += __shfl_xor(s, 8); ss += __shfl_xor(ss, 8);
    if (j == 0) {
        float mean = s * (1.f / 512.f);
        float var  = ss * (1.f / 512.f) - mean * mean;
        mv[r] = make_float2(mean, rsqrtf(var + 1e-5f));
    }
}

// ---- standalone stats from hn (final LN) ---------------------------------- (R8)
__device__ __forceinline__ void reduce_mv_hn(const unsigned short* hn,
                                             float2* mv, int tid) {
    int r = tid >> 4, j = tid & 15;
    float s = 0.f, ss = 0.f;
#pragma unroll
    for (int u = 0; u < 4; ++u) {
        uint4 pv = *(const uint4*)(hn + r * HN_STRIDE + (j + 16 * u) * 8);
        acc_u32(pv.x, s, ss); acc_u32(pv.y, s, ss);
        acc_u32(pv.z, s, ss); acc_u32(pv.w, s, ss);
    }
    s += __shfl_xor(s, 1); ss += __shfl_xor(ss, 1);
    s += __shfl_xor(s, 2); ss += __shfl_xor(ss, 2);
    s += __shfl_xor(s, 4); ss += __shfl_xor(ss, 4);
    s += __shfl_xor(s, 8); ss += __shfl_xor(ss, 8);
    if (j == 0) {
        float mean = s * (1.f / 512.f);
        float var  = ss * (1.f / 512.f) - mean * mean;
        mv[r] = make_float2(mean, rsqrtf(var + 1e-5f));
    }
}

__global__ __launch_bounds__(1024, 4) void mlp_fused(
        const float* __restrict__ x,
        const float* __restrict__ in_w,  const float* __restrict__ in_b,
        const float* __restrict__ out_ln_g, const float* __restrict__ out_ln_b,
        const float* __restrict__ out_w, const float* __restrict__ out_b,
        const unsigned short* __restrict__ wpk,
        const float* __restrict__ uv,
        float* __restrict__ out) {
    extern __shared__ char smem[];
    unsigned short* hn = (unsigned short*)smem;                  // 66560 B
    float* hnf = (float*)smem;                                   // alias (final)
    float2* mv = (float2*)(smem + 64 * HN_STRIDE * 2);           //   512 B

    const int tid = threadIdx.x;
    const int w  = tid >> 6;           // wave 0..15
    const int rh = w >> 3;             // row half: rows [rh*32, rh*32+32)
    const int cg = w & 7;              // col group: cols [cg*64, cg*64+64)
    const int l = tid & 63, c = l & 15, q = l >> 4;
    const int colbase = cg * 64 + c * 4;
    const int rbase = rh * 32;
    const int row0 = blockIdx.x * 64;

    float h[2][4][4];   // [rb][i][t] : row rbase+rb*16+q*4+i, col colbase+t

    // ---- in-proj + SiLU ----
    {
        fvec4 iw0 = *(const fvec4*)(in_w + colbase);
        fvec4 iw1 = *(const fvec4*)(in_w + 512 + colbase);
        fvec4 ib  = *(const fvec4*)(in_b + colbase);
#pragma unroll
        for (int rb = 0; rb < 2; ++rb)
#pragma unroll
            for (int i = 0; i < 4; ++i) {
                int row = rbase + rb * 16 + q * 4 + i;
                float2 xv = *(const float2*)(x + (size_t)(row0 + row) * 2);
#pragma unroll
                for (int t = 0; t < 4; ++t)
                    h[rb][i][t] = silu_f(xv.x * iw0[t] + xv.y * iw1[t] + ib[t]);
            }
    }

    for (int b = 0; b < 20; ++b) {
        const unsigned short* wp1 = wpk + (size_t)(b * 16 + cg) * WCHUNK;
        const unsigned short* wp2 = wpk + (size_t)(b * 16 + 8 + cg) * WCHUNK;
        fvec4 u1  = *(const fvec4*)(uv + ((b * 2 + 0) * 2 + 0) * 512 + colbase);
        fvec4 vc1 = *(const fvec4*)(uv + ((b * 2 + 0) * 2 + 1) * 512 + colbase);
        fvec4 u2  = *(const fvec4*)(uv + ((b * 2 + 1) * 2 + 0) * 512 + colbase);
        fvec4 vc2 = *(const fvec4*)(uv + ((b * 2 + 1) * 2 + 1) * 512 + colbase);

        // phase A: hn = bf16(h) (packed cast) + prefetch gemm1 kc=0 B-frags
        uint4 pre[4];
#pragma unroll
        for (int t = 0; t < 4; ++t) pre[t] = ((const uint4*)wp1)[t * 64 + l];
#pragma unroll
        for (int rb = 0; rb < 2; ++rb)
#pragma unroll
            for (int i = 0; i < 4; ++i) {
                int row = rbase + rb * 16 + q * 4 + i;
                *(uint2*)(hn + row * HN_STRIDE + colbase) =
                    make_uint2(pkbf(h[rb][i][0], h[rb][i][1]),
                               pkbf(h[rb][i][2], h[rb][i][3]));
            }
        __syncthreads();                               // bar1

        fvec4 acc[2][4];
#pragma unroll
        for (int rb = 0; rb < 2; ++rb)
#pragma unroll
            for (int t = 0; t < 4; ++t) acc[rb][t] = (fvec4){0.f, 0.f, 0.f, 0.f};
        gemm_red(acc, hn, wp1, pre, mv, l, c, q, tid, rbase);
        __syncthreads();                               // bar2 (mv1 + hn reads done)

        // epilogue1: t = silu(inv*acc - inv*m*u1 + vc1) -> hn ; prefetch gemm2
#pragma unroll
        for (int t = 0; t < 4; ++t) pre[t] = ((const uint4*)wp2)[t * 64 + l];
#pragma unroll
        for (int rb = 0; rb < 2; ++rb)
#pragma unroll
            for (int i = 0; i < 4; ++i) {
                int row = rbase + rb * 16 + q * 4 + i;
                float2 m = mv[row];
                float inv = m.y, minv = -m.x * m.y;
                float t0 = silu_f(__builtin_fmaf(acc[rb][0][i], inv,
                                  __builtin_fmaf(minv, u1[0], vc1[0])));
                float t1 = silu_f(__builtin_fmaf(acc[rb][1][i], inv,
                                  __builtin_fmaf(minv, u1[1], vc1[1])));
                float t2 = silu_f(__builtin_fmaf(acc[rb][2][i], inv,
                                  __builtin_fmaf(minv, u1[2], vc1[2])));
                float t3 = silu_f(__builtin_fmaf(acc[rb][3][i], inv,
                                  __builtin_fmaf(minv, u1[3], vc1[3])));
                *(uint2*)(hn + row * HN_STRIDE + colbase) =
                    make_uint2(pkbf(t0, t1), pkbf(t2, t3));
            }
        __syncthreads();                               // bar3

#pragma unroll
        for (int rb = 0; rb < 2; ++rb)
#pragma unroll
            for (int t = 0; t < 4; ++t) acc[rb][t] = (fvec4){0.f, 0.f, 0.f, 0.f};
        gemm_red(acc, hn, wp2, pre, mv, l, c, q, tid, rbase);
        __syncthreads();                               // bar4 (mv2 + hn reads done)

        // epilogue2: h += inv*acc - inv*m*u2 + vc2   (residual in fp32)
#pragma unroll
        for (int rb = 0; rb < 2; ++rb)
#pragma unroll
            for (int i = 0; i < 4; ++i) {
                int row = rbase + rb * 16 + q * 4 + i;
                float2 m = mv[row];
                float inv = m.y, minv = -m.x * m.y;
#pragma unroll
                for (int t = 0; t < 4; ++t)
                    h[rb][i][t] = __builtin_fmaf(acc[rb][t][i], inv,
                        h[rb][i][t] + __builtin_fmaf(minv, u2[t], vc2[t]));
            }
    }

    // ---- final LN + SiLU + out-proj ----
#pragma unroll
    for (int rb = 0; rb < 2; ++rb)
#pragma unroll
        for (int i = 0; i < 4; ++i) {
            int row = rbase + rb * 16 + q * 4 + i;
            *(uint2*)(hn + row * HN_STRIDE + colbase) =
                make_uint2(pkbf(h[rb][i][0], h[rb][i][1]),
                           pkbf(h[rb][i][2], h[rb][i][3]));
        }
    __syncthreads();
    reduce_mv_hn(hn, mv, tid);
    __syncthreads();
    {
        fvec4 og = *(const fvec4*)(out_ln_g + colbase);
        fvec4 ob = *(const fvec4*)(out_ln_b + colbase);
        fvec4 ow = *(const fvec4*)(out_w + colbase);
        const int scol = cg * 16 + c;           // 0..127, 4 cols each
#pragma unroll
        for (int rb = 0; rb < 2; ++rb)
#pragma unroll
            for (int i = 0; i < 4; ++i) {
                int row = rbase + rb * 16 + q * 4 + i;
                float2 m = mv[row];
                float sacc = 0.f;
#pragma unroll
                for (int t = 0; t < 4; ++t) {
                    float v = (h[rb][i][t] - m.x) * m.y * og[t] + ob[t];
                    sacc += silu_f(v) * ow[t];
                }
                hnf[scol * 65 + row] = sacc;
            }
    }
    __syncthreads();
    {
        int r = tid >> 4, j = tid & 15;
        float s = 0.f;
#pragma unroll
        for (int u = 0; u < 8; ++u)
            s += hnf[(j + 16 * u) * 65 + r];
        s += __shfl_xor(s, 1);
        s += __shfl_xor(s, 2);
        s += __shfl_xor(s, 4);
        s += __shfl_xor(s, 8);
        if (j == 0) out[row0 + r] = s + out_b[0];
    }
}

extern "C" void kernel_launch(void* const* d_in, const int* in_sizes, int n_in,
                              void* d_out, int out_size, void* d_ws, size_t ws_size,
                              hipStream_t stream) {
    const float* x        = (const float*)d_in[0];
    const float* in_w     = (const float*)d_in[1];
    const float* in_b     = (const float*)d_in[2];
    const float* ln1_g    = (const float*)d_in[3];
    const float* ln1_b    = (const float*)d_in[4];
    const float* fc1_w    = (const float*)d_in[5];
    const float* fc1_b    = (const float*)d_in[6];
    const float* ln2_g    = (const float*)d_in[7];
    const float* ln2_b    = (const float*)d_in[8];
    const float* fc2_w    = (const float*)d_in[9];
    const float* fc2_b    = (const float*)d_in[10];
    const float* out_ln_g = (const float*)d_in[11];
    const float* out_ln_b = (const float*)d_in[12];
    const float* out_w    = (const float*)d_in[13];
    const float* out_b    = (const float*)d_in[14];
    float* out = (float*)d_out;
    unsigned short* wpk = (unsigned short*)d_ws;            // 20,971,520 B
    float* uv = (float*)((char*)d_ws + WPK_USHORTS * 2);    //    163,840 B

    (void)hipFuncSetAttribute((const void*)mlp_fused,
                              hipFuncAttributeMaxDynamicSharedMemorySize, SMEM_BYTES);

    pack_weights<<<5120, 256, 0, stream>>>(fc1_w, fc2_w, ln1_g, ln2_g, wpk);
    make_uv<<<40, 512, 0, stream>>>(fc1_w, fc2_w, ln1_g, ln1_b, fc1_b,
                                    ln2_g, ln2_b, fc2_b, uv);
    mlp_fused<<<1024, 1024, SMEM_BYTES, stream>>>(
        x, in_w, in_b, out_ln_g, out_ln_b, out_w, out_b, wpk, uv, out);
}

// Round 4
// 2056.046 us; speedup vs baseline: 1.0052x; 1.0052x over previous
//
#include <hip/hip_runtime.h>
#include <hip/hip_bf16.h>

// ---------------------------------------------------------------------------
// Fused residual-MLP (N=65536, HID=512, NB=20) for gfx950.  Round 12.
//
// R11 post-mortem: 32x64/wave tiling halved A-LDS (conflicts 1.8e8->0.95e8)
// but doubled B-L2 (both row-halves pull the same 64-col chunk): sum-model
// 32k vs 28.8k cyc/unit -> 1.11x slower, measured 1.09x. Model validated;
// R8's 64x32/wave is the A<->B optimum under the 128-reg wall.
// R12 = exact R8 structure (best verified) + ONE change:
//   depth-3 software-pipelined B ring in gemm_red. kc loop fully unrolled ->
//   ring slot is compile-time (no scratch, rule #20); 2 kc of B (4 loads)
//   stay in flight -> compiler emits counted vmcnt (T4 idiom) and the
//   ~200-300cyc L2 latency per kc stops serializing the phase.
//   Reg audit: 64 arch + 32 AGPR measured in R8; ring adds ~16 -> <=112 of
//   128 cap. Spill alarm = WRITE_SIZE >> 68 MB.
// ---------------------------------------------------------------------------

typedef float  fvec4 __attribute__((ext_vector_type(4)));
typedef __bf16 bvec8 __attribute__((ext_vector_type(8)));

#define HN_STRIDE 520                 // ushorts per hn row (proven R1-R8)
#define WCHUNK    16384               // ushorts per (b,slot,w) weight chunk
#define SMEM_BYTES (64*HN_STRIDE*2 + 64*8)       // 66560 + 512 = 67072
#define WPK_USHORTS ((size_t)20*2*16*WCHUNK)     // 10,485,760

__device__ __forceinline__ unsigned int f2bf(float v) {
    unsigned int u = __float_as_uint(v);
    return (u + 0x7fffu + ((u >> 16) & 1u)) >> 16;   // RNE to bf16
}
__device__ __forceinline__ unsigned int pkbf(float a, float b) {
    __hip_bfloat162 t = __float22bfloat162_rn(make_float2(a, b));
    unsigned int r;
    __builtin_memcpy(&r, &t, 4);                     // v_cvt_pk_bf16_f32
    return r;
}
__device__ __forceinline__ float silu_f(float v) {
    return v * (1.0f / (1.0f + __expf(-v)));
}

// ---- weight pre-pack: bf16(gamma_k * W[b][k][n]) in MFMA B-fragment order -
__global__ __launch_bounds__(256) void pack_weights(
        const float* __restrict__ w1, const float* __restrict__ w2,
        const float* __restrict__ g1, const float* __restrict__ g2,
        unsigned short* __restrict__ pk) {
    int tid = blockIdx.x * 256 + threadIdx.x;
    int l  = tid & 63;
    int f  = tid >> 6;
    int t  = f & 1;
    int kc = (f >> 1) & 15;
    int w  = (f >> 5) & 15;
    int g  = (f >> 9) & 1;
    int b  = f >> 10;
    const float* src = g ? w2 : w1;
    const float* gs  = (g ? g2 : g1) + b * 512;
    int k0 = kc * 32 + (l >> 4) * 8;
    int n  = w * 32 + (l & 15) * 2 + t;
    const float* s = src + ((size_t)b * 512 + k0) * 512 + n;
    unsigned int r[4];
#pragma unroll
    for (int j = 0; j < 4; ++j) {
        float ga = gs[k0 + 2 * j];
        float gb = gs[k0 + 2 * j + 1];
        unsigned int lo = f2bf(ga * s[(size_t)(2*j) * 512]);
        unsigned int hi = f2bf(gb * s[(size_t)(2*j + 1) * 512]);
        r[j] = lo | (hi << 16);
    }
    *(uint4*)(pk + (size_t)tid * 8) = make_uint4(r[0], r[1], r[2], r[3]);
}

// ---- u/vc precompute: u_n = sum_j g_j W_jn ; vc_n = sum_j beta_j W_jn + fcb_n
__global__ __launch_bounds__(512) void make_uv(
        const float* __restrict__ w1, const float* __restrict__ w2,
        const float* __restrict__ g1, const float* __restrict__ bl1,
        const float* __restrict__ cb1,
        const float* __restrict__ g2, const float* __restrict__ bl2,
        const float* __restrict__ cb2,
        float* __restrict__ uv) {
    int b = blockIdx.x >> 1, slot = blockIdx.x & 1, n = threadIdx.x;
    const float* W  = (slot ? w2 : w1) + (size_t)b * 512 * 512;
    const float* g  = (slot ? g2 : g1) + b * 512;
    const float* bl = (slot ? bl2 : bl1) + b * 512;
    const float* cb = (slot ? cb2 : cb1) + b * 512;
    float u = 0.f, v = 0.f;
    for (int j = 0; j < 512; ++j) {
        float wv = W[(size_t)j * 512 + n];
        u = fmaf(g[j], wv, u);
        v = fmaf(bl[j], wv, v);
    }
    uv[((b * 2 + slot) * 2 + 0) * 512 + n] = u;
    uv[((b * 2 + slot) * 2 + 1) * 512 + n] = v + cb[n];
}

__device__ __forceinline__ void acc_u32(unsigned int u, float& s, float& ss) {
    float lo = __uint_as_float(u << 16);
    float hi = __uint_as_float(u & 0xFFFF0000u);
    s += lo + hi;
    ss = __builtin_fmaf(lo, lo, ss);
    ss = __builtin_fmaf(hi, hi, ss);
}

// ---- GEMM with LN-stats reduce interleaved + depth-3 B ring ---------------
// Stats of the CURRENT hn contents land in mv (visible after next barrier).
__device__ __forceinline__ void gemm_red(
        fvec4 acc[4][2], const unsigned short* hn,
        const unsigned short* __restrict__ wp, uint4 pre0, uint4 pre1,
        float2* mv, int l, int c, int q, int tid) {
    const uint4* wp4 = (const uint4*)wp;
    const int r = tid >> 4, j = tid & 15;
    float s = 0.f, ss = 0.f;
    // B ring, depth 3: slots hold kc, kc+1, kc+2. Fully-unrolled loop keeps
    // slot indices compile-time (registers, not scratch).
    uint4 rb0[3], rb1[3];
    rb0[0] = pre0;                     rb1[0] = pre1;
    rb0[1] = wp4[(1 * 2 + 0) * 64 + l]; rb1[1] = wp4[(1 * 2 + 1) * 64 + l];
    rb0[2] = wp4[(2 * 2 + 0) * 64 + l]; rb1[2] = wp4[(2 * 2 + 1) * 64 + l];
#pragma unroll
    for (int kc = 0; kc < 16; ++kc) {
        const int slot = kc % 3;       // compile-time under full unroll
        bvec8 a[4], b0, b1;
#pragma unroll
        for (int rb = 0; rb < 4; ++rb)
            a[rb] = *(const bvec8*)(hn + (rb * 16 + c) * HN_STRIDE + kc * 32 + q * 8);
        __builtin_memcpy(&b0, &rb0[slot], 16);
        __builtin_memcpy(&b1, &rb1[slot], 16);
        if (kc + 3 < 16) {             // refill the slot just consumed
            rb0[slot] = wp4[((kc + 3) * 2 + 0) * 64 + l];
            rb1[slot] = wp4[((kc + 3) * 2 + 1) * 64 + l];
        }
        if (kc >= 4 && kc < 8) {   // 4 stats chunks hidden under the MFMA stream
            uint4 pv = *(const uint4*)(hn + r * HN_STRIDE + (j + 16 * (kc - 4)) * 8);
            acc_u32(pv.x, s, ss); acc_u32(pv.y, s, ss);
            acc_u32(pv.z, s, ss); acc_u32(pv.w, s, ss);
        }
#pragma unroll
        for (int rb = 0; rb < 4; ++rb) {
            acc[rb][0] = __builtin_amdgcn_mfma_f32_16x16x32_bf16(a[rb], b0, acc[rb][0], 0, 0, 0);
            acc[rb][1] = __builtin_amdgcn_mfma_f32_16x16x32_bf16(a[rb], b1, acc[rb][1], 0, 0, 0);
        }
    }
    s += __shfl_xor(s, 1); ss += __shfl_xor(ss, 1);
    s += __shfl_xor(s, 2); ss += __shfl_xor(ss, 2);
    s += __shfl_xor(s, 4); ss += __shfl_xor(ss, 4);
    s += __shfl_xor(s, 8); ss += __shfl_xor(ss, 8);
    if (j == 0) {
        float mean = s * (1.f / 512.f);
        float var  = ss * (1.f / 512.f) - mean * mean;
        mv[r] = make_float2(mean, rsqrtf(var + 1e-5f));
    }
}

// ---- standalone stats from hn (final LN) ----------------------------------
__device__ __forceinline__ void reduce_mv_hn(const unsigned short* hn,
                                             float2* mv, int tid) {
    int r = tid >> 4, j = tid & 15;
    float s = 0.f, ss = 0.f;
#pragma unroll
    for (int u = 0; u < 4; ++u) {
        uint4 pv = *(const uint4*)(hn + r * HN_STRIDE + (j + 16 * u) * 8);
        acc_u32(pv.x, s, ss); acc_u32(pv.y, s, ss);
        acc_u32(pv.z, s, ss); acc_u32(pv.w, s, ss);
    }
    s += __shfl_xor(s, 1); ss += __shfl_xor(ss, 1);
    s += __shfl_xor(s, 2); ss += __shfl_xor(ss, 2);
    s += __shfl_xor(s, 4); ss += __shfl_xor(ss, 4);
    s += __shfl_xor(s, 8); ss += __shfl_xor(ss, 8);
    if (j == 0) {
        float mean = s * (1.f / 512.f);
        float var  = ss * (1.f / 512.f) - mean * mean;
        mv[r] = make_float2(mean, rsqrtf(var + 1e-5f));
    }
}

__global__ __launch_bounds__(1024, 4) void mlp_fused(
        const float* __restrict__ x,
        const float* __restrict__ in_w,  const float* __restrict__ in_b,
        const float* __restrict__ out_ln_g, const float* __restrict__ out_ln_b,
        const float* __restrict__ out_w, const float* __restrict__ out_b,
        const unsigned short* __restrict__ wpk,
        const float* __restrict__ uv,
        float* __restrict__ out) {
    extern __shared__ char smem[];
    unsigned short* hn = (unsigned short*)smem;                  // 66560 B
    float* hnf = (float*)smem;                                   // alias (final)
    float2* mv = (float2*)(smem + 64 * HN_STRIDE * 2);           //   512 B

    const int tid = threadIdx.x;
    const int w = tid >> 6;            // wave 0..15 -> cols [32w, 32w+32)
    const int l = tid & 63, c = l & 15, q = l >> 4;
    const int colbase = w * 32 + c * 2;
    const int row0 = blockIdx.x * 64;

    float h[4][4][2];   // [rb][i][t] : row rb*16+q*4+i, col colbase+t

    // ---- in-proj + SiLU ----
    {
        float2 iw0 = *(const float2*)(in_w + colbase);
        float2 iw1 = *(const float2*)(in_w + 512 + colbase);
        float2 ib  = *(const float2*)(in_b + colbase);
#pragma unroll
        for (int rb = 0; rb < 4; ++rb)
#pragma unroll
            for (int i = 0; i < 4; ++i) {
                int row = rb * 16 + q * 4 + i;
                float2 xv = *(const float2*)(x + (size_t)(row0 + row) * 2);
                h[rb][i][0] = silu_f(xv.x * iw0.x + xv.y * iw1.x + ib.x);
                h[rb][i][1] = silu_f(xv.x * iw0.y + xv.y * iw1.y + ib.y);
            }
    }

    for (int b = 0; b < 20; ++b) {
        const unsigned short* wp1 = wpk + ((size_t)(b * 2 + 0) * 16 + w) * WCHUNK;
        const unsigned short* wp2 = wpk + ((size_t)(b * 2 + 1) * 16 + w) * WCHUNK;
        float2 u1  = *(const float2*)(uv + ((b * 2 + 0) * 2 + 0) * 512 + colbase);
        float2 vc1 = *(const float2*)(uv + ((b * 2 + 0) * 2 + 1) * 512 + colbase);
        float2 u2  = *(const float2*)(uv + ((b * 2 + 1) * 2 + 0) * 512 + colbase);
        float2 vc2 = *(const float2*)(uv + ((b * 2 + 1) * 2 + 1) * 512 + colbase);

        // phase A: hn = bf16(h) (packed cast) + prefetch gemm1 kc=0 B-frags
        uint4 pre0 = ((const uint4*)wp1)[l];
        uint4 pre1 = ((const uint4*)wp1)[64 + l];
#pragma unroll
        for (int rb = 0; rb < 4; ++rb)
#pragma unroll
            for (int i = 0; i < 4; ++i) {
                int row = rb * 16 + q * 4 + i;
                *(unsigned int*)(hn + row * HN_STRIDE + colbase) =
                    pkbf(h[rb][i][0], h[rb][i][1]);
            }
        __syncthreads();                               // bar1

        fvec4 acc[4][2];
#pragma unroll
        for (int rb = 0; rb < 4; ++rb)
#pragma unroll
            for (int t = 0; t < 2; ++t) acc[rb][t] = (fvec4){0.f, 0.f, 0.f, 0.f};
        gemm_red(acc, hn, wp1, pre0, pre1, mv, l, c, q, tid);
        __syncthreads();                               // bar2 (mv1 + hn reads done)

        // epilogue1: t = silu(inv*acc - inv*m*u1 + vc1) -> hn ; prefetch gemm2
        pre0 = ((const uint4*)wp2)[l];
        pre1 = ((const uint4*)wp2)[64 + l];
#pragma unroll
        for (int rb = 0; rb < 4; ++rb)
#pragma unroll
            for (int i = 0; i < 4; ++i) {
                int row = rb * 16 + q * 4 + i;
                float2 m = mv[row];
                float minv = -m.x * m.y;
                float t0 = silu_f(__builtin_fmaf(acc[rb][0][i], m.y,
                                  __builtin_fmaf(minv, u1.x, vc1.x)));
                float t1 = silu_f(__builtin_fmaf(acc[rb][1][i], m.y,
                                  __builtin_fmaf(minv, u1.y, vc1.y)));
                *(unsigned int*)(hn + row * HN_STRIDE + colbase) = pkbf(t0, t1);
            }
        __syncthreads();                               // bar3

#pragma unroll
        for (int rb = 0; rb < 4; ++rb)
#pragma unroll
            for (int t = 0; t < 2; ++t) acc[rb][t] = (fvec4){0.f, 0.f, 0.f, 0.f};
        gemm_red(acc, hn, wp2, pre0, pre1, mv, l, c, q, tid);
        __syncthreads();                               // bar4 (mv2 + hn reads done)

        // epilogue2: h += inv*acc - inv*m*u2 + vc2   (residual in fp32)
#pragma unroll
        for (int rb = 0; rb < 4; ++rb)
#pragma unroll
            for (int i = 0; i < 4; ++i) {
                int row = rb * 16 + q * 4 + i;
                float2 m = mv[row];
                float minv = -m.x * m.y;
                h[rb][i][0] = __builtin_fmaf(acc[rb][0][i], m.y,
                    h[rb][i][0] + __builtin_fmaf(minv, u2.x, vc2.x));
                h[rb][i][1] = __builtin_fmaf(acc[rb][1][i], m.y,
                    h[rb][i][1] + __builtin_fmaf(minv, u2.y, vc2.y));
            }
    }

    // ---- final LN + SiLU + out-proj ----
#pragma unroll
    for (int rb = 0; rb < 4; ++rb)
#pragma unroll
        for (int i = 0; i < 4; ++i) {
            int row = rb * 16 + q * 4 + i;
            *(unsigned int*)(hn + row * HN_STRIDE + colbase) =
                pkbf(h[rb][i][0], h[rb][i][1]);
        }
    __syncthreads();
    reduce_mv_hn(hn, mv, tid);
    __syncthreads();
    {
        float2 og = *(const float2*)(out_ln_g + colbase);
        float2 ob = *(const float2*)(out_ln_b + colbase);
        float2 ow = *(const float2*)(out_w + colbase);
        const int pcol = w * 16 + c;
#pragma unroll
    for (int rb = 0; rb < 4; ++rb)
#pragma unroll
            for (int i = 0; i < 4; ++i) {
                int row = rb * 16 + q * 4 + i;
                float2 m = mv[row];
                float v0 = (h[rb][i][0] - m.x) * m.y * og.x + ob.x;
                float v1 = (h[rb][i][1] - m.x) * m.y * og.y + ob.y;
                hnf[pcol * 65 + row] = silu_f(v0) * ow.x + silu_f(v1) * ow.y;
            }
    }
    __syncthreads();
    {
        int r = tid >> 4, j = tid & 15;
        float s = 0.f;
#pragma unroll
        for (int u = 0; u < 16; ++u)
            s += hnf[(j + 16 * u) * 65 + r];
        s += __shfl_xor(s, 1);
        s += __shfl_xor(s, 2);
        s += __shfl_xor(s, 4);
        s += __shfl_xor(s, 8);
        if (j == 0) out[row0 + r] = s + out_b[0];
    }
}

extern "C" void kernel_launch(void* const* d_in, const int* in_sizes, int n_in,
                              void* d_out, int out_size, void* d_ws, size_t ws_size,
                              hipStream_t stream) {
    const float* x        = (const float*)d_in[0];
    const float* in_w     = (const float*)d_in[1];
    const float* in_b     = (const float*)d_in[2];
    const float* ln1_g    = (const float*)d_in[3];
    const float* ln1_b    = (const float*)d_in[4];
    const float* fc1_w    = (const float*)d_in[5];
    const float* fc1_b    = (const float*)d_in[6];
    const float* ln2_g    = (const float*)d_in[7];
    const float* ln2_b    = (const float*)d_in[8];
    const float* fc2_w    = (const float*)d_in[9];
    const float* fc2_b    = (const float*)d_in[10];
    const float* out_ln_g = (const float*)d_in[11];
    const float* out_ln_b = (const float*)d_in[12];
    const float* out_w    = (const float*)d_in[13];
    const float* out_b    = (const float*)d_in[14];
    float* out = (float*)d_out;
    unsigned short* wpk = (unsigned short*)d_ws;            // 20,971,520 B
    float* uv = (float*)((char*)d_ws + WPK_USHORTS * 2);    //    163,840 B

    (void)hipFuncSetAttribute((const void*)mlp_fused,
                              hipFuncAttributeMaxDynamicSharedMemorySize, SMEM_BYTES);

    pack_weights<<<5120, 256, 0, stream>>>(fc1_w, fc2_w, ln1_g, ln2_g, wpk);
    make_uv<<<40, 512, 0, stream>>>(fc1_w, fc2_w, ln1_g, ln1_b, fc1_b,
                                    ln2_g, ln2_b, fc2_b, uv);
    mlp_fused<<<1024, 1024, SMEM_BYTES, stream>>>(
        x, in_w, in_b, out_ln_g, out_ln_b, out_w, out_b, wpk, uv, out);
}